// Round 4
// baseline (450.825 us; speedup 1.0000x reference)
//
#include <hip/hip_runtime.h>
#include <math.h>

// Conv2dSelfAttention MI355X — round 4: barrier-free attn (V from L2), pipelined prep.
// B=16, C=512, N=4096, M=1024, CB=64, CG=256.

typedef unsigned short u16;
typedef short bf16x8 __attribute__((ext_vector_type(8)));
typedef float f32x16 __attribute__((ext_vector_type(16)));
typedef float f32x4v __attribute__((ext_vector_type(4)));
typedef u16 u16x4 __attribute__((ext_vector_type(4)));
typedef int i32x4 __attribute__((ext_vector_type(4)));

#define MFMA32 __builtin_amdgcn_mfma_f32_32x32x16_bf16
#define B_ 16
#define C_ 512
#define N_ 4096
#define M_ 1024
#define LOG2E 1.44269504088896f

__device__ __forceinline__ u16 f2b(float f) {  // fp32 -> bf16 RNE
  unsigned u = __float_as_uint(f);
  return (u16)((u + 0x7FFFu + ((u >> 16) & 1u)) >> 16);
}
__device__ __forceinline__ unsigned cvtpk(float a, float b) {  // lo=a, hi=b
  unsigned r;
  asm("v_cvt_pk_bf16_f32 %0, %1, %2" : "=v"(r) : "v"(a), "v"(b));
  return r;
}
__device__ __forceinline__ void permswap(unsigned &a, unsigned &b) {
  asm("v_permlane32_swap_b32 %0, %1" : "+v"(a), "+v"(b));
}
__device__ __forceinline__ float exp2v(float a) {
  float r;
  asm("v_exp_f32 %0, %1" : "=v"(r) : "v"(a));
  return r;
}
__device__ __forceinline__ f32x16 fz16() {
  f32x16 z;
#pragma unroll
  for (int i = 0; i < 16; ++i) z[i] = 0.0f;
  return z;
}

// ---------------- all weights fp32 -> bf16 in one launch ----------------
// regions (in float4 units): th[0,8192) *LOG2E | ph[8192,16384) | g[16384,49152)
// | wo[49152,81920) *gamma
__global__ __launch_bounds__(256) void cvt_all_kernel(
    const float* __restrict__ w_theta, const float* __restrict__ w_phi,
    const float* __restrict__ w_g, const float* __restrict__ w_out,
    const float* __restrict__ gamma, u16* __restrict__ dth, u16* __restrict__ dph,
    u16* __restrict__ dg, u16* __restrict__ dwo) {
  int i = blockIdx.x * 256 + threadIdx.x;
  const float* s;
  u16* d;
  float scale;
  int j;
  if (i < 8192) {
    s = w_theta; d = dth; scale = LOG2E; j = i;
  } else if (i < 16384) {
    s = w_phi; d = dph; scale = 1.0f; j = i - 8192;
  } else if (i < 49152) {
    s = w_g; d = dg; scale = 1.0f; j = i - 16384;
  } else {
    s = w_out; d = dwo; scale = gamma[0]; j = i - 49152;
  }
  float4 v = *(const float4*)(s + 4 * (size_t)j);
  u16x4 o = {f2b(v.x * scale), f2b(v.y * scale), f2b(v.z * scale), f2b(v.w * scale)};
  *(u16x4*)(d + 4 * (size_t)j) = o;
}

// ---------------- fused prep: transpose + pool + theta/phi/g convs ----------------
// grid (32 nb, 16 b), 256 thr. 8 c-chunks of 64, double-buffered LDS,
// 2-chunk-deep register prefetch of x. th [B][N][64] (log2e-scaled),
// ph [B][M][64], vt [B][256][M].
__global__ __launch_bounds__(256) void prep_kernel(
    const float* __restrict__ x, const u16* __restrict__ wth,
    const u16* __restrict__ wph, const u16* __restrict__ wg,
    const float* __restrict__ bth, const float* __restrict__ bph,
    const float* __restrict__ bg, u16* __restrict__ th, u16* __restrict__ ph,
    u16* __restrict__ vt) {
  __shared__ u16 xb[2][128 * 68];   // [n][c] bf16 tile
  __shared__ u16 xpt[2][32 * 68];   // [m][c] pooled bf16 tile
  const int t = threadIdx.x;
  const int w = t >> 6, l = t & 63, lo = l & 31, hi = l >> 5;
  const int nb = blockIdx.x, b = blockIdx.y;
  const int n0 = nb * 128, m0 = nb * 32;
  const int sc = t >> 2, sg = t & 3;  // staging: c-row, n-col group of 32

  f32x16 a_th0 = fz16(), a_th1 = fz16(), a_g0 = fz16(), a_g1 = fz16(), a_ph = fz16();

  auto loadv = [&](float* v, int c0) {
    const float* xr = x + ((size_t)(b * C_ + c0 + sc)) * N_ + n0 + sg * 32;
#pragma unroll
    for (int i = 0; i < 8; ++i) {
      f32x4v f = __builtin_nontemporal_load((const f32x4v*)(xr + 4 * i));
      v[4 * i] = f.x; v[4 * i + 1] = f.y; v[4 * i + 2] = f.z; v[4 * i + 3] = f.w;
    }
  };
  auto writeT = [&](int buf, const float* v) {
#pragma unroll
    for (int jj = 0; jj < 32; ++jj) {  // transpose (staggered rows)
      int j = (jj + 8 * sg) & 31;
      xb[buf][(sg * 32 + j) * 68 + sc] = f2b(v[j]);
    }
    float p[16];
#pragma unroll
    for (int j = 0; j < 16; ++j) p[j] = v[2 * j] + v[2 * j + 1];
#pragma unroll
    for (int j = 0; j < 16; ++j) p[j] += __shfl_xor(p[j], 2, 64);
    if (sg < 2) {
#pragma unroll
      for (int j = 0; j < 16; ++j)
        xpt[buf][(sg * 16 + j) * 68 + sc] = f2b(0.25f * p[j]);
    }
  };
  auto domfma = [&](int buf, int c0) {
    const u16* xbw = &xb[buf][(32 * w + lo) * 68 + hi * 8];
    const u16* xpw = &xpt[buf][lo * 68 + hi * 8];
    const u16* wthp = wth + (size_t)lo * C_ + c0 + hi * 8;
    const u16* wphp = wph + (size_t)(32 * w + lo) * C_ + c0 + hi * 8;
    const u16* wgp = wg + (size_t)(64 * w + lo) * C_ + c0 + hi * 8;
#pragma unroll
    for (int kh = 0; kh < 4; ++kh) {
      bf16x8 xa = *(const bf16x8*)(xbw + kh * 16);
      bf16x8 xp8 = *(const bf16x8*)(xpw + kh * 16);
      bf16x8 w0 = *(const bf16x8*)(wthp + kh * 16);
      bf16x8 w1 = *(const bf16x8*)(wthp + (size_t)32 * C_ + kh * 16);
      a_th0 = MFMA32(xa, w0, a_th0, 0, 0, 0);
      a_th1 = MFMA32(xa, w1, a_th1, 0, 0, 0);
      bf16x8 g0 = *(const bf16x8*)(wgp + kh * 16);
      bf16x8 g1 = *(const bf16x8*)(wgp + (size_t)32 * C_ + kh * 16);
      a_g0 = MFMA32(g0, xp8, a_g0, 0, 0, 0);
      a_g1 = MFMA32(g1, xp8, a_g1, 0, 0, 0);
      if (w < 2) {
        bf16x8 wp = *(const bf16x8*)(wphp + kh * 16);
        a_ph = MFMA32(xp8, wp, a_ph, 0, 0, 0);
      }
    }
  };

  float vA[32], vB[32];
  loadv(vA, 0);
  loadv(vB, 64);
  for (int i = 0; i < 8; i += 2) {
    writeT(0, vA);                       // waits only on vA's loads
    if (i + 2 < 8) loadv(vA, (i + 2) * 64);
    __syncthreads();
    domfma(0, i * 64);
    writeT(1, vB);
    if (i + 3 < 8) loadv(vB, (i + 3) * 64);
    __syncthreads();
    domfma(1, (i + 1) * 64);
  }

  int rr[16];
#pragma unroll
  for (int r = 0; r < 16; ++r) rr[r] = (r & 3) + 8 * (r >> 2) + 4 * hi;

#pragma unroll
  for (int r = 0; r < 16; ++r) {  // theta: rows n, cols o (contig in lo)
    size_t row = ((size_t)b * N_ + n0 + 32 * w + rr[r]) * 64;
    th[row + lo] = f2b(a_th0[r] + LOG2E * bth[lo]);
    th[row + 32 + lo] = f2b(a_th1[r] + LOG2E * bth[32 + lo]);
  }
#pragma unroll
  for (int r = 0; r < 16; ++r) {  // g -> vt[cg][m]
    int cg0 = 64 * w + rr[r];
    vt[((size_t)b * 256 + cg0) * M_ + m0 + lo] = f2b(a_g0[r] + bg[cg0]);
    vt[((size_t)b * 256 + cg0 + 32) * M_ + m0 + lo] = f2b(a_g1[r] + bg[cg0 + 32]);
  }
  if (w < 2) {
#pragma unroll
    for (int r = 0; r < 16; ++r) {  // phi: rows m, cols o
      size_t row = ((size_t)b * M_ + m0 + rr[r]) * 64;
      ph[row + 32 * w + lo] = f2b(a_ph[r] + bph[32 * w + lo]);
    }
  }
}

// ---------------- fused attention + out-conv + residual ----------------
// grid (32, 16) XCD-swizzled: 128 q/block, 4 waves x 32 q, m-chunks of 64.
// NO loop LDS, NO barriers: phi/V read direct from global (L2-resident).
// wo is gamma-pre-scaled.
__global__ __launch_bounds__(256, 2) void attn_kernel(const u16* __restrict__ th,
                                                      const u16* __restrict__ ph,
                                                      const u16* __restrict__ vt,
                                                      const u16* __restrict__ wo,
                                                      const float* __restrict__ b_out,
                                                      const float* __restrict__ gamma,
                                                      const float* __restrict__ x,
                                                      float* __restrict__ out) {
  __shared__ u16 Os[32768];  // 64KB epilogue O-tile only (wave-private regions)

  const int t = threadIdx.x;
  const int w = t >> 6, l = t & 63, lo = l & 31, hi = l >> 5;
  // bijective XCD swizzle: keep each batch's vt/ph on 1 XCD's L2
  const int flat = blockIdx.y * 32 + blockIdx.x;
  const int nf = (flat & 7) * 64 + (flat >> 3);
  const int b = nf >> 5, n0 = (nf & 31) * 128;
  const int qw = n0 + 32 * w;

  int rr[16];
#pragma unroll
  for (int r = 0; r < 16; ++r) rr[r] = (r & 3) + 8 * (r >> 2) + 4 * hi;

  bf16x8 thB[4];  // theta B-frags (col=q=lo, k=cb), log2e-scaled
  {
    const u16* tp = th + ((size_t)(b * N_ + qw + lo) * 64 + 8 * hi);
#pragma unroll
    for (int kh = 0; kh < 4; ++kh) thB[kh] = *(const bf16x8*)(tp + kh * 16);
  }

  f32x16 acc[8];
#pragma unroll
  for (int ct = 0; ct < 8; ++ct) acc[ct] = fz16();
  float m_run = 0.0f, l_run = 0.0f;

  for (int ic = 0; ic < 16; ++ic) {
    const int mc = ic * 64;

    // QK^T swapped: S^T tiles (m lane-spread over regs, q = lo per lane)
    f32x16 S0 = fz16(), S1 = fz16();
    const u16* pp = ph + ((size_t)(b * M_ + mc + lo) * 64 + 8 * hi);
#pragma unroll
    for (int kh = 0; kh < 4; ++kh) {
      bf16x8 p0 = *(const bf16x8*)(pp + kh * 16);
      bf16x8 p1 = *(const bf16x8*)(pp + 32 * 64 + kh * 16);
      S0 = MFMA32(p0, thB[kh], S0, 0, 0, 0);
      S1 = MFMA32(p1, thB[kh], S1, 0, 0, 0);
    }

    // online softmax, exp2 domain; in-lane tree + hi-partner shuffle
    float mp[16];
#pragma unroll
    for (int i = 0; i < 16; ++i) mp[i] = fmaxf(S0[i], S1[i]);
#pragma unroll
    for (int s = 8; s; s >>= 1)
#pragma unroll
      for (int i = 0; i < s; ++i) mp[i] = fmaxf(mp[i], mp[i + s]);
    float mx = fmaxf(mp[0], __shfl_xor(mp[0], 32, 64));

    if (__any(mx > m_run + 11.0f)) {  // defer-max (T13, log2 units)
      float nm = fmaxf(m_run, mx);
      float sc = exp2v(m_run - nm);
      m_run = nm;
      l_run *= sc;
#pragma unroll
      for (int r = 0; r < 16; ++r) {
        float scr = __shfl(sc, rr[r], 64);
#pragma unroll
        for (int ct = 0; ct < 8; ++ct) acc[ct][r] *= scr;
      }
    }

    float sp[16];
#pragma unroll
    for (int i = 0; i < 16; ++i) {
      S0[i] = exp2v(S0[i] - m_run);
      S1[i] = exp2v(S1[i] - m_run);
      sp[i] = S0[i] + S1[i];
    }
#pragma unroll
    for (int s = 8; s; s >>= 1)
#pragma unroll
      for (int i = 0; i < s; ++i) sp[i] += sp[i + s];
    l_run += sp[0] + __shfl_xor(sp[0], 32, 64);

    // P -> bf16 A-frags in-register (cvt_pk + permlane32_swap)
    bf16x8 Pf[4];
#pragma unroll
    for (int mt = 0; mt < 2; ++mt) {
#pragma unroll
      for (int s = 0; s < 2; ++s) {
        const f32x16& S = mt ? S1 : S0;
        unsigned a0 = cvtpk(S[8 * s + 0], S[8 * s + 1]);
        unsigned a1 = cvtpk(S[8 * s + 2], S[8 * s + 3]);
        unsigned a2 = cvtpk(S[8 * s + 4], S[8 * s + 5]);
        unsigned a3 = cvtpk(S[8 * s + 6], S[8 * s + 7]);
        permswap(a0, a2);
        permswap(a1, a3);
        i32x4 wv = {(int)a0, (int)a1, (int)a2, (int)a3};
        Pf[mt * 2 + s] = __builtin_bit_cast(bf16x8, wv);
      }
    }

    // PV: acc[ct] += P @ V, V-frags direct from L2 (vt[cg][m], 16B/lane)
    __builtin_amdgcn_s_setprio(1);
    const u16* vbase = vt + ((size_t)(b * 256 + lo)) * M_ + mc + 8 * hi;
#pragma unroll
    for (int ct = 0; ct < 8; ++ct) {
      const u16* vp = vbase + (size_t)(32 * ct) * M_;
      bf16x8 vf[4];
#pragma unroll
      for (int kh = 0; kh < 4; ++kh) vf[kh] = *(const bf16x8*)(vp + 16 * kh);
#pragma unroll
      for (int kh = 0; kh < 4; ++kh)
        acc[ct] = MFMA32(Pf[kh], vf[kh], acc[ct], 0, 0, 0);
    }
    __builtin_amdgcn_s_setprio(0);
  }

  float linv = 1.0f / l_run;
  float linv_r[16];
#pragma unroll
  for (int r = 0; r < 16; ++r) linv_r[r] = __shfl(linv, rr[r], 64);

  // write normalized O tile [128 q][256 cg] bf16, XOR-swizzled rows.
  // Each wave writes AND reads only its own 32 q rows -> no barrier.
#pragma unroll
  for (int ct = 0; ct < 8; ++ct)
#pragma unroll
    for (int r = 0; r < 16; ++r) {
      int q = 32 * w + rr[r];
      int blk = (4 * ct + (lo >> 3)) ^ (rr[r] & 7);
      Os[q * 256 + blk * 8 + (lo & 7)] = f2b(acc[ct][r] * linv_r[r]);
    }

  bf16x8 Bf[16];
#pragma unroll
  for (int kh = 0; kh < 16; ++kh) {
    int blk = (2 * kh + hi) ^ (lo & 7);
    Bf[kh] = *(const bf16x8*)(&Os[(32 * w + lo) * 256 + blk * 8]);
  }

  const float gamma0 = gamma[0];
#pragma unroll 2
  for (int ct = 0; ct < 16; ++ct) {
    f32x16 facc = fz16();
    const u16* wp = wo + (size_t)(32 * ct + lo) * 256 + 8 * hi;
#pragma unroll
    for (int kh = 0; kh < 16; ++kh) {
      bf16x8 af = *(const bf16x8*)(wp + kh * 16);
      facc = MFMA32(af, Bf[kh], facc, 0, 0, 0);  // wo gamma-pre-scaled
    }
#pragma unroll
    for (int r = 0; r < 16; ++r) {
      int c = 32 * ct + rr[r];
      size_t idx = ((size_t)(b * C_ + c)) * N_ + n0 + 32 * w + lo;
      float xv = __builtin_nontemporal_load(&x[idx]);
      __builtin_nontemporal_store(facc[r] + gamma0 * b_out[c] + xv, &out[idx]);
    }
  }
}

extern "C" void kernel_launch(void* const* d_in, const int* in_sizes, int n_in,
                              void* d_out, int out_size, void* d_ws, size_t ws_size,
                              hipStream_t stream) {
  (void)in_sizes; (void)n_in; (void)out_size; (void)ws_size;
  const float* x       = (const float*)d_in[0];
  const float* w_theta = (const float*)d_in[1];
  const float* b_theta = (const float*)d_in[2];
  const float* w_phi   = (const float*)d_in[3];
  const float* b_phi   = (const float*)d_in[4];
  const float* w_g     = (const float*)d_in[5];
  const float* b_g     = (const float*)d_in[6];
  const float* w_out   = (const float*)d_in[7];
  const float* b_out   = (const float*)d_in[8];
  const float* gamma   = (const float*)d_in[9];
  float* out = (float*)d_out;

  char* ws = (char*)d_ws;
  u16* th  = (u16*)(ws);               // 16*4096*64*2  = 8,388,608
  u16* ph  = (u16*)(ws + 8388608);     // 16*1024*64*2  = 2,097,152
  u16* vt  = (u16*)(ws + 10485760);    // 16*256*1024*2 = 8,388,608
  u16* wth = (u16*)(ws + 18874368);    // 65,536
  u16* wph = (u16*)(ws + 18939904);    // 65,536
  u16* wg  = (u16*)(ws + 19005440);    // 262,144
  u16* wo  = (u16*)(ws + 19267584);    // 262,144 (end 19,529,728)

  cvt_all_kernel<<<320, 256, 0, stream>>>(w_theta, w_phi, w_g, w_out, gamma,
                                          wth, wph, wg, wo);
  prep_kernel<<<dim3(32, 16), 256, 0, stream>>>(x, wth, wph, wg, b_theta, b_phi,
                                                b_g, th, ph, vt);
  attn_kernel<<<dim3(32, 16), 256, 0, stream>>>(th, ph, vt, wo, b_out, gamma, x, out);
}

// Round 5
// 232.330 us; speedup vs baseline: 1.9404x; 1.9404x over previous
//
#include <hip/hip_runtime.h>
#include <math.h>

// Conv2dSelfAttention MI355X — round 5: fragment-linear tiled operands.
// Every MFMA operand load in attn/prep is coalesced (base + lane*16B).
// attn: zero LDS, zero barriers; softmax scaling lane-scalar via transposed PV.
// B=16, C=512, N=4096, M=1024, CB=64, CG=256.

typedef unsigned short u16;
typedef short bf16x8 __attribute__((ext_vector_type(8)));
typedef float f32x16 __attribute__((ext_vector_type(16)));
typedef u16 u16x4 __attribute__((ext_vector_type(4)));
typedef int i32x4 __attribute__((ext_vector_type(4)));

#define MFMA32 __builtin_amdgcn_mfma_f32_32x32x16_bf16
#define B_ 16
#define C_ 512
#define N_ 4096
#define M_ 1024
#define LOG2E 1.44269504088896f

__device__ __forceinline__ u16 f2b(float f) {  // fp32 -> bf16 RNE
  unsigned u = __float_as_uint(f);
  return (u16)((u + 0x7FFFu + ((u >> 16) & 1u)) >> 16);
}
__device__ __forceinline__ unsigned cvtpk(float a, float b) {  // lo=a, hi=b
  unsigned r;
  asm("v_cvt_pk_bf16_f32 %0, %1, %2" : "=v"(r) : "v"(a), "v"(b));
  return r;
}
__device__ __forceinline__ void permswap(unsigned &a, unsigned &b) {
  asm("v_permlane32_swap_b32 %0, %1" : "+v"(a), "+v"(b));
}
__device__ __forceinline__ float exp2v(float a) {
  float r;
  asm("v_exp_f32 %0, %1" : "=v"(r) : "v"(a));
  return r;
}
__device__ __forceinline__ f32x16 fz16() {
  f32x16 z;
#pragma unroll
  for (int i = 0; i < 16; ++i) z[i] = 0.0f;
  return z;
}

// Fragment-linear layouts (lane l = hi*32+lo, e = 0..7):
//  weights [O][512] (A or B op):  fW(o,c) = (((o>>5)*8 + (c>>6))*4 + ((c>>4)&3))*512
//                                           + (((c>>3)&1)*32 + (o&31))*8 + (c&7)
//  wo [512][256]:    fWO(c,k) = ((c>>5)*16 + (k>>4))*512 + (((k>>3)&1)*32 + (c&31))*8 + (k&7)
//  th [b][n][cb]:    ((nb*4+w)*4+kh)*512 + l*8 + e     (nb=n>>7, w=(n>>5)&3)
//  ph [b][m][cb]:    ((ic*2+mt)*4+kh)*512 + l*8 + e    (ic=m>>6, mt=(m>>5)&1)
//  vt [b][cg][m]:    ((ic*8+ct)*4+kh)*512 + l*8 + e    (ct=cg>>5, kh=(m>>4)&3)

// ---------------- weights fp32 -> bf16, tiled ----------------
__global__ __launch_bounds__(256) void cvt_all_kernel(
    const float* __restrict__ w_theta, const float* __restrict__ w_phi,
    const float* __restrict__ w_g, const float* __restrict__ w_out,
    const float* __restrict__ gamma, u16* __restrict__ dth, u16* __restrict__ dph,
    u16* __restrict__ dg, u16* __restrict__ dwo) {
  int i = blockIdx.x * 256 + threadIdx.x;
  if (i < 16384) {  // wth / wph : 64 x 512
    const float* s = (i < 8192) ? w_theta : w_phi;
    u16* d = (i < 8192) ? dth : dph;
    float scale = (i < 8192) ? LOG2E : 1.0f;
    int j = i & 8191;
    int o = j >> 7, c = (j & 127) * 4;
    float4 vv = *(const float4*)(s + (size_t)o * 512 + c);
    int idx = (((o >> 5) * 8 + (c >> 6)) * 4 + ((c >> 4) & 3)) * 512 +
              (((c >> 3) & 1) * 32 + (o & 31)) * 8 + (c & 7);
    u16x4 ot = {f2b(vv.x * scale), f2b(vv.y * scale), f2b(vv.z * scale), f2b(vv.w * scale)};
    *(u16x4*)(d + idx) = ot;
  } else if (i < 49152) {  // wg : 256 x 512
    int j = i - 16384;
    int o = j >> 7, c = (j & 127) * 4;
    float4 vv = *(const float4*)(w_g + (size_t)o * 512 + c);
    int idx = (((o >> 5) * 8 + (c >> 6)) * 4 + ((c >> 4) & 3)) * 512 +
              (((c >> 3) & 1) * 32 + (o & 31)) * 8 + (c & 7);
    u16x4 ot = {f2b(vv.x), f2b(vv.y), f2b(vv.z), f2b(vv.w)};
    *(u16x4*)(dg + idx) = ot;
  } else {  // wo : 512 x 256, gamma-prescaled
    int j = i - 49152;
    int o = j >> 6, k = (j & 63) * 4;
    float scale = gamma[0];
    float4 vv = *(const float4*)(w_out + (size_t)o * 256 + k);
    int idx = ((o >> 5) * 16 + (k >> 4)) * 512 +
              (((k >> 3) & 1) * 32 + (o & 31)) * 8 + (k & 7);
    u16x4 ot = {f2b(vv.x * scale), f2b(vv.y * scale), f2b(vv.z * scale), f2b(vv.w * scale)};
    *(u16x4*)(dwo + idx) = ot;
  }
}

// ---------------- fused prep: transpose + pool + theta/phi/g convs ----------------
// grid (32 nb, 16 b), 256 thr. 8 c-chunks of 64; x loads issued one chunk ahead.
__global__ __launch_bounds__(256) void prep_kernel(
    const float* __restrict__ x, const u16* __restrict__ wth,
    const u16* __restrict__ wph, const u16* __restrict__ wg,
    const float* __restrict__ bth, const float* __restrict__ bph,
    const float* __restrict__ bg, u16* __restrict__ th, u16* __restrict__ ph,
    u16* __restrict__ vt) {
  __shared__ u16 xb[128 * 68];   // [n][c-local], c-blocks XOR-swizzled by (n>>2)&7
  __shared__ u16 xpt[32 * 68];   // [m][c-local]
  const int t = threadIdx.x;
  const int w = t >> 6, l = t & 63, lo = l & 31, hi = l >> 5;
  const int nb = blockIdx.x, b = blockIdx.y;
  const int n0 = nb * 128;
  const int lcol = (t & 31) * 4;  // n within 128
  const int lrow = t >> 5;        // c-row 0..7

  f32x16 a_th0 = fz16(), a_th1 = fz16(), a_g0 = fz16(), a_g1 = fz16(), a_ph = fz16();

  float v[32];
  auto loadv = [&](int c0) {
    const float* xr = x + ((size_t)(b * C_ + c0 + lrow)) * N_ + n0 + lcol;
#pragma unroll
    for (int i = 0; i < 8; ++i) {
      float4 f = *(const float4*)(xr + (size_t)(8 * i) * N_);
      v[4*i] = f.x; v[4*i+1] = f.y; v[4*i+2] = f.z; v[4*i+3] = f.w;
    }
  };
  auto writeT = [&]() {
#pragma unroll
    for (int i = 0; i < 8; ++i)
#pragma unroll
      for (int k = 0; k < 4; ++k) {
        int n = lcol + k;
        xb[n * 68 + ((i ^ ((n >> 2) & 7)) * 8) + lrow] = f2b(v[4*i+k]);
      }
    float p[16];
#pragma unroll
    for (int i = 0; i < 8; ++i) {
      p[2*i]   = v[4*i]   + v[4*i+1];
      p[2*i+1] = v[4*i+2] + v[4*i+3];
    }
#pragma unroll
    for (int j = 0; j < 16; ++j) p[j] += __shfl_xor(p[j], 16, 64);
    if ((l & 31) < 16) {
#pragma unroll
      for (int i = 0; i < 8; ++i) {
        xpt[((l & 31) * 2 + 0) * 68 + lrow + 8*i] = f2b(0.25f * p[2*i]);
        xpt[((l & 31) * 2 + 1) * 68 + lrow + 8*i] = f2b(0.25f * p[2*i+1]);
      }
    }
  };
  auto domfma = [&](int c0b) {
    const int rbase = (32 * w + lo) * 68;
    const int rsw = (lo >> 2) & 7;
    const u16* xpw = &xpt[lo * 68];
#pragma unroll
    for (int kh = 0; kh < 4; ++kh) {
      bf16x8 xa  = *(const bf16x8*)(&xb[rbase + (((2*kh + hi) ^ rsw) * 8)]);
      bf16x8 xp8 = *(const bf16x8*)(xpw + kh * 16 + hi * 8);
      bf16x8 w0 = *(const bf16x8*)(wth + ((c0b) * 4 + kh) * 512 + l * 8);
      bf16x8 w1 = *(const bf16x8*)(wth + ((8 + c0b) * 4 + kh) * 512 + l * 8);
      a_th0 = MFMA32(xa, w0, a_th0, 0, 0, 0);
      a_th1 = MFMA32(xa, w1, a_th1, 0, 0, 0);
      bf16x8 g0 = *(const bf16x8*)(wg + ((16*w + c0b) * 4 + kh) * 512 + l * 8);
      bf16x8 g1 = *(const bf16x8*)(wg + ((16*w + 8 + c0b) * 4 + kh) * 512 + l * 8);
      a_g0 = MFMA32(g0, xp8, a_g0, 0, 0, 0);
      a_g1 = MFMA32(g1, xp8, a_g1, 0, 0, 0);
      if (w < 2) {
        bf16x8 wp8 = *(const bf16x8*)(wph + ((w*8 + c0b) * 4 + kh) * 512 + l * 8);
        a_ph = MFMA32(xp8, wp8, a_ph, 0, 0, 0);
      }
    }
  };

  loadv(0);
  for (int i = 0; i < 8; ++i) {
    if (i) __syncthreads();
    writeT();
    if (i < 7) loadv((i + 1) * 64);  // in flight across the MFMA phase
    __syncthreads();
    domfma(i);
  }

  int rr[16];
#pragma unroll
  for (int r = 0; r < 16; ++r) rr[r] = (r & 3) + 8 * (r >> 2) + 4 * hi;

  // th (tiled): element (n = n0+32w+rr, cb)
  u16* thb = th + (size_t)b * 262144;
#pragma unroll
  for (int r = 0; r < 16; ++r) {
    int sub = (((lo >> 3) & 1) * 32 + rr[r]) * 8 + (lo & 7);
    thb[((nb*4 + w)*4 + (lo >> 4)) * 512 + sub]     = f2b(a_th0[r] + LOG2E * bth[lo]);
    thb[((nb*4 + w)*4 + 2 + (lo >> 4)) * 512 + sub] = f2b(a_th1[r] + LOG2E * bth[32 + lo]);
  }
  // vt (tiled): element (cg = 64w(+32)+rr, m = nb*32+lo)
  u16* vtb = vt + (size_t)b * 262144;
#pragma unroll
  for (int r = 0; r < 16; ++r) {
    int cg0 = 64 * w + rr[r];
    int sub = (((lo >> 3) & 1) * 32 + rr[r]) * 8 + (lo & 7);
    int kk = (nb & 1) * 2 + (lo >> 4);
    vtb[(((nb >> 1) * 8 + 2*w) * 4 + kk) * 512 + sub]     = f2b(a_g0[r] + bg[cg0]);
    vtb[(((nb >> 1) * 8 + 2*w + 1) * 4 + kk) * 512 + sub] = f2b(a_g1[r] + bg[cg0 + 32]);
  }
  // ph (tiled): element (m = nb*32+rr, cb = 32w+lo)   [waves 0,1 only]
  if (w < 2) {
    u16* phb = ph + (size_t)b * 65536;
#pragma unroll
    for (int r = 0; r < 16; ++r) {
      int sub = (((lo >> 3) & 1) * 32 + rr[r]) * 8 + (lo & 7);
      phb[(nb*4 + 2*w + (lo >> 4)) * 512 + sub] = f2b(a_ph[r] + bph[32*w + lo]);
    }
  }
}

// ---------------- fused attention + out-conv + residual ----------------
// grid (32,16) XCD-swizzled; 128 q/block, 4 waves x 32 q; no LDS, no barriers.
// PV computed transposed (acc = V^T @ P^T) so q lives in the lane dim:
// softmax rescale/normalize lane-scalar; O packed in-register for the out-conv.
__global__ __launch_bounds__(256, 2) void attn_kernel(
    const u16* __restrict__ th, const u16* __restrict__ ph,
    const u16* __restrict__ vt, const u16* __restrict__ wo,
    const float* __restrict__ b_out, const float* __restrict__ gamma,
    const float* __restrict__ x, float* __restrict__ out) {
  const int t = threadIdx.x;
  const int w = t >> 6, l = t & 63, lo = l & 31, hi = l >> 5;
  const int flat = blockIdx.y * 32 + blockIdx.x;
  const int nf = (flat & 7) * 64 + (flat >> 3);  // bijective XCD swizzle
  const int b = nf >> 5, nb = nf & 31;
  const int n0 = nb * 128, qw = n0 + 32 * w;

  int rr[16];
#pragma unroll
  for (int r = 0; r < 16; ++r) rr[r] = (r & 3) + 8 * (r >> 2) + 4 * hi;

  bf16x8 thB[4];
  {
    const u16* thb = th + (size_t)b * 262144 + (size_t)((nb * 4 + w) * 4) * 512;
#pragma unroll
    for (int kh = 0; kh < 4; ++kh)
      thB[kh] = *(const bf16x8*)(thb + kh * 512 + l * 8);
  }
  const u16* phb = ph + (size_t)b * 65536;
  const u16* vtb = vt + (size_t)b * 262144;

  f32x16 acc[8];
#pragma unroll
  for (int ct = 0; ct < 8; ++ct) acc[ct] = fz16();
  float m_run = 0.0f, l_run = 0.0f;

  bf16x8 pfA[8], pfB[8];
#pragma unroll
  for (int j = 0; j < 8; ++j)
    pfA[j] = *(const bf16x8*)(phb + j * 512 + l * 8);

  auto body = [&](int ic, bf16x8 (&pf)[8], bf16x8 (&pfn)[8], bool pre) {
    // QK^T swapped: S^T tiles, q = lane (lo), m over regs
    f32x16 S0 = fz16(), S1 = fz16();
#pragma unroll
    for (int kh = 0; kh < 4; ++kh) {
      S0 = MFMA32(pf[kh], thB[kh], S0, 0, 0, 0);
      S1 = MFMA32(pf[4 + kh], thB[kh], S1, 0, 0, 0);
    }
    if (pre) {  // prefetch next iter's phi frags
      const u16* pn = phb + (size_t)(ic + 1) * 4096;
#pragma unroll
      for (int j = 0; j < 8; ++j)
        pfn[j] = *(const bf16x8*)(pn + j * 512 + l * 8);
    }

    // online softmax (exp2 domain), stats per lane-q
    float mp[16];
#pragma unroll
    for (int i2 = 0; i2 < 16; ++i2) mp[i2] = fmaxf(S0[i2], S1[i2]);
#pragma unroll
    for (int s = 8; s; s >>= 1)
#pragma unroll
      for (int i2 = 0; i2 < s; ++i2) mp[i2] = fmaxf(mp[i2], mp[i2 + s]);
    float mx = fmaxf(mp[0], __shfl_xor(mp[0], 32, 64));

    if (__any(mx > m_run + 11.0f)) {  // defer-max (log2 units)
      float nm = fmaxf(m_run, mx);
      float sc = exp2v(m_run - nm);
      m_run = nm;
      l_run *= sc;
#pragma unroll
      for (int ct = 0; ct < 8; ++ct)
#pragma unroll
        for (int r = 0; r < 16; ++r) acc[ct][r] *= sc;  // lane-scalar
    }

    float sp[16];
#pragma unroll
    for (int i2 = 0; i2 < 16; ++i2) {
      S0[i2] = exp2v(S0[i2] - m_run);
      S1[i2] = exp2v(S1[i2] - m_run);
      sp[i2] = S0[i2] + S1[i2];
    }
#pragma unroll
    for (int s = 8; s; s >>= 1)
#pragma unroll
      for (int i2 = 0; i2 < s; ++i2) sp[i2] += sp[i2 + s];
    l_run += sp[0] + __shfl_xor(sp[0], 32, 64);

    // P -> bf16 frags (cvt_pk + permlane32_swap); usable as B (k=m, col=q)
    bf16x8 Pf[4];
#pragma unroll
    for (int mt = 0; mt < 2; ++mt)
#pragma unroll
      for (int s = 0; s < 2; ++s) {
        const f32x16& S = mt ? S1 : S0;
        unsigned a0 = cvtpk(S[8*s+0], S[8*s+1]);
        unsigned a1 = cvtpk(S[8*s+2], S[8*s+3]);
        unsigned a2 = cvtpk(S[8*s+4], S[8*s+5]);
        unsigned a3 = cvtpk(S[8*s+6], S[8*s+7]);
        permswap(a0, a2);
        permswap(a1, a3);
        i32x4 wv = {(int)a0, (int)a1, (int)a2, (int)a3};
        Pf[mt*2+s] = __builtin_bit_cast(bf16x8, wv);
      }

    // PV transposed: acc[ct] = V^T-frag (A) @ Pf (B); all loads coalesced
    __builtin_amdgcn_s_setprio(1);
    const u16* vb = vtb + (size_t)ic * 16384;
#pragma unroll
    for (int ct = 0; ct < 8; ++ct) {
      const u16* vp = vb + ct * 2048 + l * 8;
      bf16x8 vf0 = *(const bf16x8*)(vp);
      bf16x8 vf1 = *(const bf16x8*)(vp + 512);
      bf16x8 vf2 = *(const bf16x8*)(vp + 1024);
      bf16x8 vf3 = *(const bf16x8*)(vp + 1536);
      acc[ct] = MFMA32(vf0, Pf[0], acc[ct], 0, 0, 0);
      acc[ct] = MFMA32(vf1, Pf[1], acc[ct], 0, 0, 0);
      acc[ct] = MFMA32(vf2, Pf[2], acc[ct], 0, 0, 0);
      acc[ct] = MFMA32(vf3, Pf[3], acc[ct], 0, 0, 0);
    }
    __builtin_amdgcn_s_setprio(0);
  };

  for (int ic2 = 0; ic2 < 8; ++ic2) {
    body(2 * ic2, pfA, pfB, true);
    body(2 * ic2 + 1, pfB, pfA, ic2 < 7);
  }

  // normalize + pack O^T into B-frags for the out-conv (same transform as P)
  float linv = 1.0f / l_run;
  bf16x8 Of[16];
#pragma unroll
  for (int u = 0; u < 4; ++u)
#pragma unroll
    for (int mt = 0; mt < 2; ++mt) {
      f32x16& A = acc[2*u + mt];
#pragma unroll
      for (int s = 0; s < 2; ++s) {
        unsigned a0 = cvtpk(A[8*s+0]*linv, A[8*s+1]*linv);
        unsigned a1 = cvtpk(A[8*s+2]*linv, A[8*s+3]*linv);
        unsigned a2 = cvtpk(A[8*s+4]*linv, A[8*s+5]*linv);
        unsigned a3 = cvtpk(A[8*s+6]*linv, A[8*s+7]*linv);
        permswap(a0, a2);
        permswap(a1, a3);
        i32x4 wv = {(int)a0, (int)a1, (int)a2, (int)a3};
        Of[u*4 + mt*2 + s] = __builtin_bit_cast(bf16x8, wv);
      }
    }

  // out-conv: facc = wo-frag (A, rows c) @ Of (B, k=cg, col=q); + bias + residual
  const float gamma0 = gamma[0];
#pragma unroll 2
  for (int ctc = 0; ctc < 16; ++ctc) {
    f32x16 facc = fz16();
    const u16* wp = wo + ctc * 16 * 512 + l * 8;
#pragma unroll
    for (int kh = 0; kh < 16; ++kh) {
      bf16x8 af = *(const bf16x8*)(wp + kh * 512);
      facc = MFMA32(af, Of[kh], facc, 0, 0, 0);  // wo gamma-prescaled
    }
#pragma unroll
    for (int r = 0; r < 16; ++r) {
      int c = 32 * ctc + rr[r];
      size_t idx = ((size_t)(b * C_ + c)) * N_ + qw + lo;
      float xv = __builtin_nontemporal_load(&x[idx]);
      __builtin_nontemporal_store(facc[r] + gamma0 * b_out[c] + xv, &out[idx]);
    }
  }
}

extern "C" void kernel_launch(void* const* d_in, const int* in_sizes, int n_in,
                              void* d_out, int out_size, void* d_ws, size_t ws_size,
                              hipStream_t stream) {
  (void)in_sizes; (void)n_in; (void)out_size; (void)ws_size;
  const float* x       = (const float*)d_in[0];
  const float* w_theta = (const float*)d_in[1];
  const float* b_theta = (const float*)d_in[2];
  const float* w_phi   = (const float*)d_in[3];
  const float* b_phi   = (const float*)d_in[4];
  const float* w_g     = (const float*)d_in[5];
  const float* b_g     = (const float*)d_in[6];
  const float* w_out   = (const float*)d_in[7];
  const float* b_out   = (const float*)d_in[8];
  const float* gamma   = (const float*)d_in[9];
  float* out = (float*)d_out;

  char* ws = (char*)d_ws;
  u16* th  = (u16*)(ws);               // 16*262144*2 = 8,388,608
  u16* ph  = (u16*)(ws + 8388608);     // 16*65536*2  = 2,097,152
  u16* vt  = (u16*)(ws + 10485760);    // 16*262144*2 = 8,388,608
  u16* wth = (u16*)(ws + 18874368);    // 65,536
  u16* wph = (u16*)(ws + 18939904);    // 65,536
  u16* wg  = (u16*)(ws + 19005440);    // 262,144
  u16* wo  = (u16*)(ws + 19267584);    // 262,144 (end 19,529,728)

  cvt_all_kernel<<<320, 256, 0, stream>>>(w_theta, w_phi, w_g, w_out, gamma,
                                          wth, wph, wg, wo);
  prep_kernel<<<dim3(32, 16), 256, 0, stream>>>(x, wth, wph, wg, b_theta, b_phi,
                                                b_g, th, ph, vt);
  attn_kernel<<<dim3(32, 16), 256, 0, stream>>>(th, ph, vt, wo, b_out, gamma, x, out);
}